// Round 5
// baseline (10196.989 us; speedup 1.0000x reference)
//
#include <hip/hip_runtime.h>
#include <hip/hip_bf16.h>
#include <hip/hip_fp16.h>

#define LOG2E 1.4426950408889634f

constexpr int B_ = 256, T_ = 128, IN_ = 64, U_ = 256;
constexpr int UNFOLDS = 6;

// ---- workspace layout (bytes) ----
// Records are quads over i: rec index = (k*4+q)*256 + j, covering
// i = 16k + 4q + {0,1,2,3}.  cd-plane: uint4{half2(c0,c1),half2(c2,c3),
// half2(d0,d1),half2(d2,d3)}; w-plane: uint2{half2(w0,w1),half2(w2,w3)}.
// c = sig*mu*log2e, d = sig*log2e, w = w*erev. sigmoid = 1/(1+exp2(c-d*v))
constexpr size_t OFF_RCD = 0;        // uint4[16384]  262144 B (recurrent, k<16)
constexpr size_t OFF_RW  = 262144;   // uint2[16384]  131072 B
constexpr size_t OFF_SCD = 393216;   // uint4[4096]    65536 B (sensory, k<4)
constexpr size_t OFF_SW  = 458752;   // uint2[4096]    32768 B
constexpr size_t OFF_ELF = 491520;   // float[32768]  131072 B
constexpr size_t OFF_VEC = 622592;   // float[1536]: gl[0:256] glvl[256:512]
                                     //   cm[512:768] how[768:1024] hob[1024:1280]
                                     //   inw[1280:1344] inb[1344:1408] hb[1408]

__device__ __forceinline__ float ldf(const void* p, int idx, bool isbf) {
  return isbf ? __bfloat162float(((const __hip_bfloat16*)p)[idx])
              : ((const float*)p)[idx];
}

__device__ __forceinline__ unsigned pkh2(float a, float b) {
  __half2 h; h.x = __float2half_rn(a); h.y = __float2half_rn(b);
  return __builtin_bit_cast(unsigned, h);
}

// ---------------------------------------------------------------------------
// Prep: dtype-detect (timespans all-ones: word0 0x3F803F80 => bf16), pack.
// ---------------------------------------------------------------------------
__global__ __launch_bounds__(256) void ltc_prep(
    const void* tspan, const void* smu, const void* ssigma, const void* sw,
    const void* serev, const void* mu, const void* sigma, const void* w,
    const void* erev, const void* gleak, const void* vleak, const void* cm,
    const void* inw, const void* inb, const void* outw, const void* outb,
    const void* headw, const void* headb, char* __restrict__ ws) {
  const bool isbf = (((const unsigned*)tspan)[0] == 0x3F803F80u);
  const int idx = blockIdx.x * blockDim.x + threadIdx.x;  // 0..32767

  uint4* rcd = (uint4*)(ws + OFF_RCD);
  uint2* rw  = (uint2*)(ws + OFF_RW);
  uint4* scd = (uint4*)(ws + OFF_SCD);
  uint2* swp = (uint2*)(ws + OFF_SW);
  float* elf = (float*)(ws + OFF_ELF);
  float* vec = (float*)(ws + OFF_VEC);

  if (idx < 16384) {  // recurrent quads
    const int j = idx & 255, kq = idx >> 8;               // kq = k*4+q
    const int i0 = ((kq >> 2) << 4) + ((kq & 3) << 2);    // 16k + 4q
    float c[4], d[4], wv[4];
#pragma unroll
    for (int m = 0; m < 4; ++m) {
      const int e = (i0 + m) * U_ + j;
      float sg = ldf(sigma, e, isbf), mm = ldf(mu, e, isbf);
      c[m] = sg * mm * LOG2E; d[m] = sg * LOG2E;
      wv[m] = ldf(w, e, isbf) * ldf(erev, e, isbf);
    }
    rcd[idx] = make_uint4(pkh2(c[0], c[1]), pkh2(c[2], c[3]),
                          pkh2(d[0], d[1]), pkh2(d[2], d[3]));
    rw[idx]  = make_uint2(pkh2(wv[0], wv[1]), pkh2(wv[2], wv[3]));
  }
  if (idx < 4096) {  // sensory quads (i0 < 64)
    const int j = idx & 255, kq = idx >> 8;
    const int i0 = ((kq >> 2) << 4) + ((kq & 3) << 2);
    float c[4], d[4], wv[4];
#pragma unroll
    for (int m = 0; m < 4; ++m) {
      const int e = (i0 + m) * U_ + j;
      float sg = ldf(ssigma, e, isbf), mm = ldf(smu, e, isbf);
      c[m] = sg * mm * LOG2E; d[m] = sg * LOG2E;
      wv[m] = ldf(sw, e, isbf) * ldf(serev, e, isbf);
    }
    scd[idx] = make_uint4(pkh2(c[0], c[1]), pkh2(c[2], c[3]),
                          pkh2(d[0], d[1]), pkh2(d[2], d[3]));
    swp[idx] = make_uint2(pkh2(wv[0], wv[1]), pkh2(wv[2], wv[3]));
  }
  if (idx < B_ * T_) elf[idx] = ldf(tspan, idx, isbf);
  if (idx < U_) {
    float gl = ldf(gleak, idx, isbf);
    float hw = ldf(headw, idx, isbf);
    vec[idx]        = gl;
    vec[256 + idx]  = gl * ldf(vleak, idx, isbf);
    vec[512 + idx]  = ldf(cm, idx, isbf);
    vec[768 + idx]  = ldf(outw, idx, isbf) * hw;
    vec[1024 + idx] = ldf(outb, idx, isbf) * hw;
  }
  if (idx < IN_) {
    vec[1280 + idx] = ldf(inw, idx, isbf);
    vec[1344 + idx] = ldf(inb, idx, isbf);
  }
  if (idx == 0) vec[1408] = ldf(headb, 0, isbf);
}

// 4 edges of one quad record against v4
__device__ __forceinline__ void equad(uint4 cd, uint2 wp, float4 v4,
                                      float& sn, float& sd) {
  __half2 c01 = __builtin_bit_cast(__half2, cd.x);
  __half2 c23 = __builtin_bit_cast(__half2, cd.y);
  __half2 d01 = __builtin_bit_cast(__half2, cd.z);
  __half2 d23 = __builtin_bit_cast(__half2, cd.w);
  __half2 w01 = __builtin_bit_cast(__half2, wp.x);
  __half2 w23 = __builtin_bit_cast(__half2, wp.y);
  float t0 = fmaf(-__low2float(d01),  v4.x, __low2float(c01));
  float t1 = fmaf(-__high2float(d01), v4.y, __high2float(c01));
  float t2 = fmaf(-__low2float(d23),  v4.z, __low2float(c23));
  float t3 = fmaf(-__high2float(d23), v4.w, __high2float(c23));
  float s0 = __builtin_amdgcn_rcpf(1.0f + __builtin_amdgcn_exp2f(t0));
  float s1 = __builtin_amdgcn_rcpf(1.0f + __builtin_amdgcn_exp2f(t1));
  float s2 = __builtin_amdgcn_rcpf(1.0f + __builtin_amdgcn_exp2f(t2));
  float s3 = __builtin_amdgcn_rcpf(1.0f + __builtin_amdgcn_exp2f(t3));
  float p0 = __low2float(w01)  * s0;
  float p1 = __high2float(w01) * s1;
  float p2 = __low2float(w23)  * s2;
  float p3 = __high2float(w23) * s3;
  sn += p0; sd += fabsf(p0);
  sn += p1; sd += fabsf(p1);
  sn += p2; sd += fabsf(p2);
  sn += p3; sd += fabsf(p3);
}

// ---------------------------------------------------------------------------
// Main: block = batch (grid 256 = #CUs, always 1 block/CU -> VGPRs <=128 free).
// 1024 threads: j = tid>>2 (unit), q = tid&3. Thread (j,q) covers
// i = 16k+4q+{0..3}, k<16. Reduce over q: 2x shfl_xor (lane bits 0..1).
// v double-buffered in LDS -> 1 barrier/unfold. Records k<8 register-cached
// (48 VGPRs, loop-invariant); k>=8 streamed from L2 (~14 TB/s, not binding).
// NOTE: __launch_bounds__ 2nd arg MUST stay 1 — "(1024,4)" was interpreted as
// min-blocks, clamped to 2 -> 64-VGPR cap -> full cache spill (R4: 10.7 GB
// scratch FETCH). (1024,1) keeps the 128-VGPR budget.
// ---------------------------------------------------------------------------
__global__ __launch_bounds__(1024, 1) void ltc_main(
    const void* __restrict__ x_ltc, const void* __restrict__ tspan,
    const char* __restrict__ ws, void* __restrict__ out) {
  __shared__ __attribute__((aligned(16))) float vbuf[2][U_];
  __shared__ __attribute__((aligned(16))) float x_sh[IN_];
  __shared__ float hred[1024];

  const bool isbf = (((const unsigned*)tspan)[0] == 0x3F803F80u);
  const int b = blockIdx.x, tid = threadIdx.x;
  const int j = tid >> 2, q = tid & 3;
  const int voff = q << 2;  // 4q

  const uint4* rcd = (const uint4*)(ws + OFF_RCD);
  const uint2* rw  = (const uint2*)(ws + OFF_RW);
  const uint4* scd = (const uint4*)(ws + OFF_SCD);
  const uint2* swp = (const uint2*)(ws + OFF_SW);
  const float* elf = (const float*)(ws + OFF_ELF);
  const float* vec = (const float*)(ws + OFF_VEC);

  const float r_gl   = vec[j];
  const float r_glvl = vec[256 + j];
  const float r_cm   = vec[512 + j];
  float r_inw = 0.f, r_inb = 0.f;
  if (tid < IN_) { r_inw = vec[1280 + tid]; r_inb = vec[1344 + tid]; }
  if (q == 0) vbuf[0][j] = 0.0f;

  // register-cache recurrent records k = 0..7 (loop-invariant, 48 VGPRs)
  uint4 rcA[8]; uint2 rwA[8];
#pragma unroll
  for (int k = 0; k < 8; ++k) {
    const int idx = (k * 4 + q) * 256 + j;
    rcA[k] = rcd[idx]; rwA[k] = rw[idx];
  }

  for (int t = 0; t < T_; ++t) {
    if (tid < IN_) {
      float xv = ldf(x_ltc, (b * T_ + t) * IN_ + tid, isbf);
      x_sh[tid] = fmaf(xv, r_inw, r_inb);
    }
    __syncthreads();  // x ready (also covers vbuf init at t=0)

    // ---- sensory (i0 = 16k+4q, k<4): in-wave reduce, no barrier ----
    float rn_s, rd_s;
    {
      float sn = 0.f, sd = 0.f;
#pragma unroll
      for (int k = 0; k < 4; ++k) {
        const int idx = (k * 4 + q) * 256 + j;
        float4 x4 = *(const float4*)&x_sh[16 * k + voff];
        equad(scd[idx], swp[idx], x4, sn, sd);
      }
      sn += __shfl_xor(sn, 1); sn += __shfl_xor(sn, 2);
      sd += __shfl_xor(sd, 1); sd += __shfl_xor(sd, 2);
      rn_s = sn; rd_s = sd;
    }
    const float el  = elf[b * T_ + t];
    const float cmt = r_cm * (float)UNFOLDS * __builtin_amdgcn_rcpf(el);

    // ---- unfolds: 1 barrier each ----
    int rb = 0;
#pragma unroll 1
    for (int u = 0; u < UNFOLDS; ++u) {
      const float* vr = vbuf[rb];
      float sn = 0.f, sd = 0.f;
#pragma unroll
      for (int k = 0; k < 8; ++k) {  // register-cached records
        float4 v4 = *(const float4*)&vr[16 * k + voff];
        equad(rcA[k], rwA[k], v4, sn, sd);
      }
#pragma unroll 4
      for (int k = 8; k < 16; ++k) {  // L2-served records
        const int idx = (k * 4 + q) * 256 + j;
        float4 v4 = *(const float4*)&vr[16 * k + voff];
        equad(rcd[idx], rw[idx], v4, sn, sd);
      }
      sn += __shfl_xor(sn, 1); sn += __shfl_xor(sn, 2);
      sd += __shfl_xor(sd, 1); sd += __shfl_xor(sd, 2);
      const float vj  = vr[j];
      const float num = fmaf(cmt, vj, r_glvl) + sn + rn_s;
      const float den = cmt + r_gl + sd + rd_s + 1e-8f;
      const float vn  = num * __builtin_amdgcn_rcpf(den);
      if (q == 0) vbuf[1 - rb][j] = vn;
      __syncthreads();
      rb ^= 1;
    }
  }

  // ---- head: out[b] = sum_j v_j*how_j + hob_j, + hb ----
  float hv = 0.f;
  if (tid < U_) hv = fmaf(vbuf[0][tid], vec[768 + tid], vec[1024 + tid]);
  hred[tid] = hv;
  __syncthreads();
  for (int s = 512; s > 0; s >>= 1) {
    if (tid < s) hred[tid] += hred[tid + s];
    __syncthreads();
  }
  if (tid == 0) {
    float o = hred[0] + vec[1408];
    if (isbf) ((__hip_bfloat16*)out)[b] = __float2bfloat16(o);
    else      ((float*)out)[b] = o;
  }
}

extern "C" void kernel_launch(void* const* d_in, const int* in_sizes, int n_in,
                              void* d_out, int out_size, void* d_ws, size_t ws_size,
                              hipStream_t stream) {
  (void)in_sizes; (void)n_in; (void)out_size; (void)ws_size;
  const void* x_ltc  = d_in[0];
  const void* tspan  = d_in[1];
  const void* smu    = d_in[2];
  const void* ssigma = d_in[3];
  const void* sw     = d_in[4];
  const void* serev  = d_in[5];
  const void* mu     = d_in[6];
  const void* sigma  = d_in[7];
  const void* w      = d_in[8];
  const void* erev   = d_in[9];
  const void* gleak  = d_in[10];
  const void* vleak  = d_in[11];
  const void* cmv    = d_in[12];
  const void* inw    = d_in[13];
  const void* inb    = d_in[14];
  const void* outw   = d_in[15];
  const void* outb   = d_in[16];
  const void* headw  = d_in[17];
  const void* headb  = d_in[18];

  ltc_prep<<<128, 256, 0, stream>>>(
      tspan, smu, ssigma, sw, serev, mu, sigma, w, erev,
      gleak, vleak, cmv, inw, inb, outw, outb, headw, headb, (char*)d_ws);

  ltc_main<<<B_, 1024, 0, stream>>>(x_ltc, tspan, (const char*)d_ws, d_out);
}

// Round 6
// 6929.382 us; speedup vs baseline: 1.4716x; 1.4716x over previous
//
#include <hip/hip_runtime.h>
#include <hip/hip_bf16.h>
#include <hip/hip_fp16.h>

#define LOG2E 1.4426950408889634f

constexpr int B_ = 256, T_ = 128, IN_ = 64, U_ = 256;
constexpr int UNFOLDS = 6;

// ---- workspace layout (bytes) ----
// Records are quads over i: rec index = (k*4+q)*256 + j, covering
// i = 16k + 4q + {0,1,2,3}.  cd-plane: uint4{half2(c0,c1),half2(c2,c3),
// half2(d0,d1),half2(d2,d3)}; w-plane: uint2{half2(w0,w1),half2(w2,w3)}.
// c = sig*mu*log2e, d = sig*log2e, w = w*erev. sigmoid = 1/(1+exp2(c-d*v))
constexpr size_t OFF_RCD = 0;        // uint4[16384]  262144 B (recurrent, k<16)
constexpr size_t OFF_RW  = 262144;   // uint2[16384]  131072 B
constexpr size_t OFF_SCD = 393216;   // uint4[4096]    65536 B (sensory, k<4)
constexpr size_t OFF_SW  = 458752;   // uint2[4096]    32768 B
constexpr size_t OFF_ELF = 491520;   // float[32768]  131072 B
constexpr size_t OFF_VEC = 622592;   // float[1536]: gl[0:256] glvl[256:512]
                                     //   cm[512:768] how[768:1024] hob[1024:1280]
                                     //   inw[1280:1344] inb[1344:1408] hb[1408]

__device__ __forceinline__ float ldf(const void* p, int idx, bool isbf) {
  return isbf ? __bfloat162float(((const __hip_bfloat16*)p)[idx])
              : ((const float*)p)[idx];
}

__device__ __forceinline__ unsigned pkh2(float a, float b) {
  __half2 h; h.x = __float2half_rn(a); h.y = __float2half_rn(b);
  return __builtin_bit_cast(unsigned, h);
}

// ---------------------------------------------------------------------------
// Prep: dtype-detect (timespans all-ones: word0 0x3F803F80 => bf16), pack.
// ---------------------------------------------------------------------------
__global__ __launch_bounds__(256) void ltc_prep(
    const void* tspan, const void* smu, const void* ssigma, const void* sw,
    const void* serev, const void* mu, const void* sigma, const void* w,
    const void* erev, const void* gleak, const void* vleak, const void* cm,
    const void* inw, const void* inb, const void* outw, const void* outb,
    const void* headw, const void* headb, char* __restrict__ ws) {
  const bool isbf = (((const unsigned*)tspan)[0] == 0x3F803F80u);
  const int idx = blockIdx.x * blockDim.x + threadIdx.x;  // 0..32767

  uint4* rcd = (uint4*)(ws + OFF_RCD);
  uint2* rw  = (uint2*)(ws + OFF_RW);
  uint4* scd = (uint4*)(ws + OFF_SCD);
  uint2* swp = (uint2*)(ws + OFF_SW);
  float* elf = (float*)(ws + OFF_ELF);
  float* vec = (float*)(ws + OFF_VEC);

  if (idx < 16384) {  // recurrent quads
    const int j = idx & 255, kq = idx >> 8;               // kq = k*4+q
    const int i0 = ((kq >> 2) << 4) + ((kq & 3) << 2);    // 16k + 4q
    float c[4], d[4], wv[4];
#pragma unroll
    for (int m = 0; m < 4; ++m) {
      const int e = (i0 + m) * U_ + j;
      float sg = ldf(sigma, e, isbf), mm = ldf(mu, e, isbf);
      c[m] = sg * mm * LOG2E; d[m] = sg * LOG2E;
      wv[m] = ldf(w, e, isbf) * ldf(erev, e, isbf);
    }
    rcd[idx] = make_uint4(pkh2(c[0], c[1]), pkh2(c[2], c[3]),
                          pkh2(d[0], d[1]), pkh2(d[2], d[3]));
    rw[idx]  = make_uint2(pkh2(wv[0], wv[1]), pkh2(wv[2], wv[3]));
  }
  if (idx < 4096) {  // sensory quads (i0 < 64)
    const int j = idx & 255, kq = idx >> 8;
    const int i0 = ((kq >> 2) << 4) + ((kq & 3) << 2);
    float c[4], d[4], wv[4];
#pragma unroll
    for (int m = 0; m < 4; ++m) {
      const int e = (i0 + m) * U_ + j;
      float sg = ldf(ssigma, e, isbf), mm = ldf(smu, e, isbf);
      c[m] = sg * mm * LOG2E; d[m] = sg * LOG2E;
      wv[m] = ldf(sw, e, isbf) * ldf(serev, e, isbf);
    }
    scd[idx] = make_uint4(pkh2(c[0], c[1]), pkh2(c[2], c[3]),
                          pkh2(d[0], d[1]), pkh2(d[2], d[3]));
    swp[idx] = make_uint2(pkh2(wv[0], wv[1]), pkh2(wv[2], wv[3]));
  }
  if (idx < B_ * T_) elf[idx] = ldf(tspan, idx, isbf);
  if (idx < U_) {
    float gl = ldf(gleak, idx, isbf);
    float hw = ldf(headw, idx, isbf);
    vec[idx]        = gl;
    vec[256 + idx]  = gl * ldf(vleak, idx, isbf);
    vec[512 + idx]  = ldf(cm, idx, isbf);
    vec[768 + idx]  = ldf(outw, idx, isbf) * hw;
    vec[1024 + idx] = ldf(outb, idx, isbf) * hw;
  }
  if (idx < IN_) {
    vec[1280 + idx] = ldf(inw, idx, isbf);
    vec[1344 + idx] = ldf(inb, idx, isbf);
  }
  if (idx == 0) vec[1408] = ldf(headb, 0, isbf);
}

// 4 edges of one quad record against v4
__device__ __forceinline__ void equad(uint4 cd, uint2 wp, float4 v4,
                                      float& sn, float& sd) {
  __half2 c01 = __builtin_bit_cast(__half2, cd.x);
  __half2 c23 = __builtin_bit_cast(__half2, cd.y);
  __half2 d01 = __builtin_bit_cast(__half2, cd.z);
  __half2 d23 = __builtin_bit_cast(__half2, cd.w);
  __half2 w01 = __builtin_bit_cast(__half2, wp.x);
  __half2 w23 = __builtin_bit_cast(__half2, wp.y);
  float t0 = fmaf(-__low2float(d01),  v4.x, __low2float(c01));
  float t1 = fmaf(-__high2float(d01), v4.y, __high2float(c01));
  float t2 = fmaf(-__low2float(d23),  v4.z, __low2float(c23));
  float t3 = fmaf(-__high2float(d23), v4.w, __high2float(c23));
  float s0 = __builtin_amdgcn_rcpf(1.0f + __builtin_amdgcn_exp2f(t0));
  float s1 = __builtin_amdgcn_rcpf(1.0f + __builtin_amdgcn_exp2f(t1));
  float s2 = __builtin_amdgcn_rcpf(1.0f + __builtin_amdgcn_exp2f(t2));
  float s3 = __builtin_amdgcn_rcpf(1.0f + __builtin_amdgcn_exp2f(t3));
  float p0 = __low2float(w01)  * s0;
  float p1 = __high2float(w01) * s1;
  float p2 = __low2float(w23)  * s2;
  float p3 = __high2float(w23) * s3;
  sn += p0; sd += fabsf(p0);
  sn += p1; sd += fabsf(p1);
  sn += p2; sd += fabsf(p2);
  sn += p3; sd += fabsf(p3);
}

// ---------------------------------------------------------------------------
// Main: block = batch (grid 256 = #CUs, 1 block/CU, 16 waves = exactly
// 4 waves/EU). amdgpu_waves_per_eu(4,4) pins the backend's occupancy target
// there -> 128-VGPR budget (R4/R5: default target stayed 8/EU -> 64 VGPRs ->
// the record cache spilled to scratch, 10.7 GB HBM FETCH, 607 MB WRITE).
// Three record tiers, none spillable:
//   k<6   : named-scalar registers (36 VGPRs, SROA-proof)
//   k=6,7 : LDS, per-thread slot [tid] (48 KB, wave-contiguous, no conflicts)
//   k>=8  : streamed from L2 (~196 KB/block/unfold, hidden under VALU)
// ---------------------------------------------------------------------------
__global__ __attribute__((amdgpu_waves_per_eu(4, 4))) __launch_bounds__(1024)
void ltc_main(
    const void* __restrict__ x_ltc, const void* __restrict__ tspan,
    const char* __restrict__ ws, void* __restrict__ out) {
  __shared__ __attribute__((aligned(16))) float vbuf[2][U_];
  __shared__ __attribute__((aligned(16))) float x_sh[IN_];
  __shared__ float hred[1024];
  __shared__ __attribute__((aligned(16))) uint4 cdL[2][1024];  // 32 KB
  __shared__ __attribute__((aligned(16))) uint2 wL[2][1024];   // 16 KB

  const bool isbf = (((const unsigned*)tspan)[0] == 0x3F803F80u);
  const int b = blockIdx.x, tid = threadIdx.x;
  const int j = tid >> 2, q = tid & 3;
  const int voff = q << 2;  // 4q

  const uint4* rcd = (const uint4*)(ws + OFF_RCD);
  const uint2* rw  = (const uint2*)(ws + OFF_RW);
  const uint4* scd = (const uint4*)(ws + OFF_SCD);
  const uint2* swp = (const uint2*)(ws + OFF_SW);
  const float* elf = (const float*)(ws + OFF_ELF);
  const float* vec = (const float*)(ws + OFF_VEC);

  const float r_gl   = vec[j];
  const float r_glvl = vec[256 + j];
  const float r_cm   = vec[512 + j];
  float r_inw = 0.f, r_inb = 0.f;
  if (tid < IN_) { r_inw = vec[1280 + tid]; r_inb = vec[1344 + tid]; }
  if (q == 0) vbuf[0][j] = 0.0f;

  // ---- tier 1: named-scalar register cache, k = 0..5 (36 VGPRs) ----
#define RIDX(K) (((K) * 4 + q) * 256 + j)
  const uint4 rc0 = rcd[RIDX(0)], rc1 = rcd[RIDX(1)], rc2 = rcd[RIDX(2)],
              rc3 = rcd[RIDX(3)], rc4 = rcd[RIDX(4)], rc5 = rcd[RIDX(5)];
  const uint2 rw0 = rw[RIDX(0)], rw1 = rw[RIDX(1)], rw2 = rw[RIDX(2)],
              rw3 = rw[RIDX(3)], rw4 = rw[RIDX(4)], rw5 = rw[RIDX(5)];
  // ---- tier 2: LDS cache, k = 6,7 (per-thread private slot) ----
  cdL[0][tid] = rcd[RIDX(6)]; wL[0][tid] = rw[RIDX(6)];
  cdL[1][tid] = rcd[RIDX(7)]; wL[1][tid] = rw[RIDX(7)];

  for (int t = 0; t < T_; ++t) {
    if (tid < IN_) {
      float xv = ldf(x_ltc, (b * T_ + t) * IN_ + tid, isbf);
      x_sh[tid] = fmaf(xv, r_inw, r_inb);
    }
    __syncthreads();  // x ready (also covers vbuf init / LDS cache fill at t=0)

    // ---- sensory (i0 = 16k+4q, k<4): in-wave reduce, no barrier ----
    float rn_s, rd_s;
    {
      float sn = 0.f, sd = 0.f;
#pragma unroll
      for (int k = 0; k < 4; ++k) {
        float4 x4 = *(const float4*)&x_sh[16 * k + voff];
        equad(scd[RIDX(k)], swp[RIDX(k)], x4, sn, sd);
      }
      sn += __shfl_xor(sn, 1); sn += __shfl_xor(sn, 2);
      sd += __shfl_xor(sd, 1); sd += __shfl_xor(sd, 2);
      rn_s = sn; rd_s = sd;
    }
    const float el  = elf[b * T_ + t];
    const float cmt = r_cm * (float)UNFOLDS * __builtin_amdgcn_rcpf(el);

    // ---- unfolds: 1 barrier each ----
    int rb = 0;
#pragma unroll 1
    for (int u = 0; u < UNFOLDS; ++u) {
      const float* vr = vbuf[rb];
      float sn = 0.f, sd = 0.f;
      // tier 1: registers (k=0..5)
      equad(rc0, rw0, *(const float4*)&vr[  0 + voff], sn, sd);
      equad(rc1, rw1, *(const float4*)&vr[ 16 + voff], sn, sd);
      equad(rc2, rw2, *(const float4*)&vr[ 32 + voff], sn, sd);
      equad(rc3, rw3, *(const float4*)&vr[ 48 + voff], sn, sd);
      equad(rc4, rw4, *(const float4*)&vr[ 64 + voff], sn, sd);
      equad(rc5, rw5, *(const float4*)&vr[ 80 + voff], sn, sd);
      // tier 2: LDS (k=6,7)
      equad(cdL[0][tid], wL[0][tid], *(const float4*)&vr[ 96 + voff], sn, sd);
      equad(cdL[1][tid], wL[1][tid], *(const float4*)&vr[112 + voff], sn, sd);
      // tier 3: L2 stream (k=8..15)
#pragma unroll 2
      for (int k = 8; k < 16; ++k) {
        float4 v4 = *(const float4*)&vr[16 * k + voff];
        equad(rcd[RIDX(k)], rw[RIDX(k)], v4, sn, sd);
      }
      sn += __shfl_xor(sn, 1); sn += __shfl_xor(sn, 2);
      sd += __shfl_xor(sd, 1); sd += __shfl_xor(sd, 2);
      const float vj  = vr[j];
      const float num = fmaf(cmt, vj, r_glvl) + sn + rn_s;
      const float den = cmt + r_gl + sd + rd_s + 1e-8f;
      const float vn  = num * __builtin_amdgcn_rcpf(den);
      if (q == 0) vbuf[1 - rb][j] = vn;
      __syncthreads();
      rb ^= 1;
    }
  }
#undef RIDX

  // ---- head: out[b] = sum_j v_j*how_j + hob_j, + hb ----
  float hv = 0.f;
  if (tid < U_) hv = fmaf(vbuf[0][tid], vec[768 + tid], vec[1024 + tid]);
  hred[tid] = hv;
  __syncthreads();
  for (int s = 512; s > 0; s >>= 1) {
    if (tid < s) hred[tid] += hred[tid + s];
    __syncthreads();
  }
  if (tid == 0) {
    float o = hred[0] + vec[1408];
    if (isbf) ((__hip_bfloat16*)out)[b] = __float2bfloat16(o);
    else      ((float*)out)[b] = o;
  }
}

extern "C" void kernel_launch(void* const* d_in, const int* in_sizes, int n_in,
                              void* d_out, int out_size, void* d_ws, size_t ws_size,
                              hipStream_t stream) {
  (void)in_sizes; (void)n_in; (void)out_size; (void)ws_size;
  const void* x_ltc  = d_in[0];
  const void* tspan  = d_in[1];
  const void* smu    = d_in[2];
  const void* ssigma = d_in[3];
  const void* sw     = d_in[4];
  const void* serev  = d_in[5];
  const void* mu     = d_in[6];
  const void* sigma  = d_in[7];
  const void* w      = d_in[8];
  const void* erev   = d_in[9];
  const void* gleak  = d_in[10];
  const void* vleak  = d_in[11];
  const void* cmv    = d_in[12];
  const void* inw    = d_in[13];
  const void* inb    = d_in[14];
  const void* outw   = d_in[15];
  const void* outb   = d_in[16];
  const void* headw  = d_in[17];
  const void* headb  = d_in[18];

  ltc_prep<<<128, 256, 0, stream>>>(
      tspan, smu, ssigma, sw, serev, mu, sigma, w, erev,
      gleak, vleak, cmv, inw, inb, outw, outb, headw, headb, (char*)d_ws);

  ltc_main<<<B_, 1024, 0, stream>>>(x_ltc, tspan, (const char*)d_ws, d_out);
}